// Round 18
// baseline (1041.494 us; speedup 1.0000x reference)
//
#include <hip/hip_runtime.h>
#include <hip/hip_bf16.h>
#include <math.h>

#define NTOK 16384   // NS*L = 8*2048
#define HDIM 1024
#define MDIM 4096
#define NEXP 8
#define EPSV 1e-9f
#define RTOK 32      // tokens per router block

typedef unsigned short u16;
typedef __attribute__((ext_vector_type(4))) float f32x4;
typedef __attribute__((ext_vector_type(8))) __bf16 bf16x8;
typedef __attribute__((ext_vector_type(8))) unsigned short u16x8;
typedef __attribute__((ext_vector_type(4))) unsigned short u16x4;

#define ASYNC_COPY16(gptr, lptr) \
    __builtin_amdgcn_global_load_lds( \
        (const __attribute__((address_space(1))) void*)(gptr), \
        (__attribute__((address_space(3))) void*)(lptr), 16, 0, 0)

static __device__ __forceinline__ u16 f2bf(float f) {
    unsigned int u = __builtin_bit_cast(unsigned int, f);
    u += 0x7fff + ((u >> 16) & 1);   // RNE
    return (u16)(u >> 16);
}

// NaN-safe tanh-approx GELU: v * sigmoid(2z), z = sqrt(2/pi)(v + 0.044715 v^3).
static __device__ __forceinline__ float gelu_f(float v) {
    float z2 = -1.5957691216f * v * (1.f + 0.044715f * v * v);
    return v / (1.f + __expf(z2));
}

// ------- router: logits -> softmax -> top2 -> expert lists; also x -> bf16 ---
__global__ __launch_bounds__(256) void router_kernel(
    const float* __restrict__ x, const float* __restrict__ Wr,
    const float* __restrict__ br,
    int* __restrict__ counts, int* __restrict__ ltok, float* __restrict__ lcf,
    u16* __restrict__ xb)
{
    __shared__ int   lcount[NEXP];
    __shared__ int   lbase[NEXP];
    __shared__ int   ltokL[NEXP][RTOK];
    __shared__ float lcfL[NEXP][RTOK];

    int t = threadIdx.x;
    if (t < NEXP) lcount[t] = 0;
    __syncthreads();

    int wave = t >> 6, lane = t & 63;

    for (int it = 0; it < RTOK / 4; ++it) {
        int tok = blockIdx.x * RTOK + it * 4 + wave;
        const float* xr = x + (size_t)tok * HDIM + lane * 16;

        f32x4 xv[4];
        #pragma unroll
        for (int q = 0; q < 4; q++) xv[q] = *reinterpret_cast<const f32x4*>(xr + q * 4);

        u16x8 ob0, ob1;
        #pragma unroll
        for (int j = 0; j < 4; j++) {
            ob0[j]     = f2bf(xv[0][j]);
            ob0[4 + j] = f2bf(xv[1][j]);
            ob1[j]     = f2bf(xv[2][j]);
            ob1[4 + j] = f2bf(xv[3][j]);
        }
        u16* xo = xb + (size_t)tok * HDIM + lane * 16;
        *reinterpret_cast<u16x8*>(xo)     = ob0;
        *reinterpret_cast<u16x8*>(xo + 8) = ob1;

        f32x4 acc0 = {0.f, 0.f, 0.f, 0.f};
        f32x4 acc1 = {0.f, 0.f, 0.f, 0.f};
        #pragma unroll
        for (int q = 0; q < 4; q++) {
            #pragma unroll
            for (int j = 0; j < 4; j++) {
                int h = lane * 16 + q * 4 + j;
                const float* wrow = Wr + (size_t)h * NEXP;
                f32x4 w0 = *reinterpret_cast<const f32x4*>(wrow);
                f32x4 w1 = *reinterpret_cast<const f32x4*>(wrow + 4);
                acc0 += xv[q][j] * w0;
                acc1 += xv[q][j] * w1;
            }
        }
        float a[NEXP];
        #pragma unroll
        for (int e = 0; e < 4; e++) { a[e] = acc0[e]; a[4 + e] = acc1[e]; }
        #pragma unroll
        for (int e = 0; e < NEXP; e++) {
            #pragma unroll
            for (int s = 1; s < 64; s <<= 1) a[e] += __shfl_xor(a[e], s, 64);
        }
        if (lane == 0) {
            float l[NEXP], m = -1e30f;
            #pragma unroll
            for (int e = 0; e < NEXP; e++) { l[e] = a[e] + br[e]; m = fmaxf(m, l[e]); }
            float p[NEXP], s = 0.f;
            #pragma unroll
            for (int e = 0; e < NEXP; e++) { p[e] = expf(l[e] - m); s += p[e]; }
            int i0 = 0; float v0 = p[0];
            #pragma unroll
            for (int e = 1; e < NEXP; e++) if (p[e] > v0) { v0 = p[e]; i0 = e; }
            int i1 = -1; float v1 = -1.f;
            #pragma unroll
            for (int e = 0; e < NEXP; e++) if (e != i0 && p[e] > v1) { v1 = p[e]; i1 = e; }
            v0 /= s; v1 /= s;
            float sw = v0 + v1;
            float w0 = v0 / (sw + EPSV), w1 = v1 / (sw + EPSV);
            float wa = w0 + w1;
            float c0 = w0 / (wa + EPSV), c1 = w1 / (wa + EPSV);
            int q0 = atomicAdd(&lcount[i0], 1);
            ltokL[i0][q0] = tok; lcfL[i0][q0] = c0;
            int q1 = atomicAdd(&lcount[i1], 1);
            ltokL[i1][q1] = tok; lcfL[i1][q1] = c1;
        }
    }
    __syncthreads();
    if (t < NEXP) lbase[t] = atomicAdd(&counts[t], lcount[t]);
    __syncthreads();
    #pragma unroll
    for (int e = 0; e < NEXP; e++) {
        int n = lcount[e], b = lbase[e];
        for (int j = t; j < n; j += 256) {
            ltok[e * NTOK + b + j] = ltokL[e][j];
            lcf[e * NTOK + b + j]  = lcfL[e][j];
        }
    }
}

// ---------------- prefix sum of counts -> slot bases --------------------------
__global__ void bases_kernel(const int* __restrict__ counts, int* __restrict__ bases)
{
    if (threadIdx.x == 0) {
        int acc = 0;
        #pragma unroll
        for (int e = 0; e < NEXP; e++) { bases[e] = acc; acc += counts[e]; }
    }
}

// -------- fused transpose+convert for W1 and W2 (one dispatch, z selects) ----
__global__ __launch_bounds__(256) void transpose_cvt_kernel(
    const float* __restrict__ W1, const float* __restrict__ W2,
    u16* __restrict__ w1t, u16* __restrict__ w2t)
{
    __shared__ float tile[32][33];
    int z = blockIdx.z;
    int R, C;
    const float* ine;
    u16* oute;
    if (z < NEXP) {
        R = HDIM; C = MDIM;
        ine  = W1 + (size_t)z * R * C;
        oute = w1t + (size_t)z * R * C;
    } else {
        R = MDIM; C = HDIM;
        ine  = W2 + (size_t)(z - NEXP) * R * C;
        oute = w2t + (size_t)(z - NEXP) * R * C;
    }
    int tiles_x = C >> 5;
    int ti = blockIdx.x;
    int c0 = (ti & (tiles_x - 1)) * 32;
    int r0 = (ti / tiles_x) * 32;

    int t = threadIdx.x;
    int r = t >> 3, cq = t & 7;
    f32x4 v = *reinterpret_cast<const f32x4*>(ine + (size_t)(r0 + r) * C + c0 + cq * 4);
    #pragma unroll
    for (int j = 0; j < 4; j++) tile[r][cq * 4 + j] = v[j];
    __syncthreads();
    int c = t >> 3, rq = t & 7;
    u16x4 o;
    #pragma unroll
    for (int j = 0; j < 4; j++) o[j] = f2bf(tile[rq * 4 + j][c]);
    *reinterpret_cast<u16x4*>(oute + (size_t)(c0 + c) * R + r0 + rq * 4) = o;
}

// ==== grouped MFMA GEMM: 256x128 tile, BK=32, single-buffered (24 KB LDS ->
//      4 blocks/CU = 32 waves = FULL wave cap), R13 loop structure, XCD chunk
//      swizzle (x-fastest), R10's refcheck'd 64B-row LDS XOR swizzle.
//      512 threads = 8 waves of 64x64.
// R18 change vs R13: BK 64->32 halves LDS (48->24 KB), doubling resident
//   blocks 2->4; the per-K-step vmcnt(0)+barrier drain is then overlapped by
//   3 other blocks' compute (attacks the measured 35-40% occupancy deficit).
// Per K-step per wave: 3 global_load_lds -> __syncthreads -> 8 ds_read_b128
//   + 16 MFMA -> __syncthreads.
// LDS swizzle (64B rows, 4x16B chunks): slot (row,c) holds logical chunk
//   c ^ ((row>>1)&3); source pre-swizzled; reads use (lg ^ ((lr>>1)&3)).
// EPI==0: hmid[(bases[e]+pos)][col] = gelu(acc + b1[e][col]); A gathered by ltok
// EPI==1: atomicAdd(out[ltok[pos]][col], lcf[pos]*(acc + b2[e][col]))
template<int EPI, int GX, int GY>
__global__ __launch_bounds__(512) void gemm_kernel(
    const u16* __restrict__ A,          // bf16; row stride = Astride
    const u16* __restrict__ BT_all,     // (NEXP x P x K) bf16
    const float* __restrict__ bias_all, // (NEXP x P)
    const int* __restrict__ counts,
    const int* __restrict__ bases,
    const int* __restrict__ ltok,       // (NEXP x NTOK)
    const float* __restrict__ lcf,      // (NEXP x NTOK)
    u16* __restrict__ hmid,
    float* __restrict__ out,
    int K, int P, int Astride, int eStart)
{
    // ---- XCD chunk swizzle (bijective; nwg % 8 == 0 in all our launches) ----
    int gz = gridDim.z;
    int nwg = GX * GY * gz;
    int orig = blockIdx.x + GX * (blockIdx.y + GY * blockIdx.z);
    int qq = nwg >> 3, rr = nwg & 7;
    int xcd = orig & 7, sub = orig >> 3;
    int wgid = (xcd < rr ? xcd * (qq + 1) : rr * (qq + 1) + (xcd - rr) * qq) + sub;
    int bx = wgid & (GX - 1);
    int rem = wgid / GX;
    int by = rem & (GY - 1);
    int bz = rem / GY;

    int e = eStart + bz;
    int nrows = counts[e];
    int row0 = by * 256;
    if (row0 >= nrows) return;          // uniform across block, before barriers
    int p0 = bx * 128;
    int slotbase = bases[e];
    const u16*   BT   = BT_all + (size_t)e * P * K;
    const float* bias = bias_all + (size_t)e * P;
    const int*   lte  = ltok + (size_t)e * NTOK;
    const float* lcfe = lcf  + (size_t)e * NTOK;

    __shared__ u16 As[256][32];   // 16 KB, single-buffered
    __shared__ u16 Bs[128][32];   //  8 KB

    int t = threadIdx.x;
    int wv = t >> 6, lane = t & 63;     // 8 waves

    // staging geometry (R10's refcheck'd 64B-row swizzle): thread t covers
    // row rl = t>>2 within a 128-row slab, chunk ch = t&3; source chunk
    // pre-swizzled so LDS slot (row,c) holds logical chunk c ^ ((row>>1)&3).
    int rl = t >> 2, ch = t & 3;        // rl 0..127
    int sc = ch ^ ((rl >> 1) & 3);
    const u16* aptr[2];                 // A rows rl and 128+rl
    const u16* bptr;                    // B row rl
    #pragma unroll
    for (int i = 0; i < 2; i++) {
        int pos  = row0 + i * 128 + rl;
        int posc = min(pos, nrows - 1);
        int arow = (EPI == 0) ? lte[posc] : (slotbase + posc);
        aptr[i] = A + (size_t)arow * Astride + sc * 8;
    }
    bptr = BT + (size_t)(p0 + rl) * K + sc * 8;

    // output mapping: 8 waves = 4 rows x 2 cols of 64x64 tiles
    int wr = (wv >> 1) * 64, wc = (wv & 1) * 64;
    int lr = lane & 15, lg = lane >> 4;
    int rsw = (lg ^ ((lr >> 1) & 3)) * 8;   // read chunk offset (u16 units)

    f32x4 acc[4][4];
    #pragma unroll
    for (int m = 0; m < 4; m++)
        #pragma unroll
        for (int nn = 0; nn < 4; nn++) acc[m][nn] = (f32x4){0.f, 0.f, 0.f, 0.f};

    for (int k0 = 0; k0 < K; k0 += 32) {
        // wave wv's lanes cover rows wv*16..wv*16+15 (lane>>2) x 4 chunks:
        // dest = &As[slab + wv*16][0] + lane*16B (16 rows x 64B = 1KB) ✓
        #pragma unroll
        for (int i = 0; i < 2; i++)
            ASYNC_COPY16(aptr[i] + k0, &As[i * 128 + wv * 16][0]);
        ASYNC_COPY16(bptr + k0, &Bs[wv * 16][0]);
        __syncthreads();   // drains vmcnt: tile resident

        bf16x8 af[4], bf[4];
        #pragma unroll
        for (int m = 0; m < 4; m++)
            af[m] = *reinterpret_cast<const bf16x8*>(&As[wr + m * 16 + lr][rsw]);
        #pragma unroll
        for (int nn = 0; nn < 4; nn++)
            bf[nn] = *reinterpret_cast<const bf16x8*>(&Bs[wc + nn * 16 + lr][rsw]);
        #pragma unroll
        for (int m = 0; m < 4; m++)
            #pragma unroll
            for (int nn = 0; nn < 4; nn++)
                acc[m][nn] = __builtin_amdgcn_mfma_f32_16x16x32_bf16(
                    af[m], bf[nn], acc[m][nn], 0, 0, 0);
        __syncthreads();   // reads done before next overwrite
    }

    // D mapping (m89-verified): col = lane&15, row = (lane>>4)*4 + reg
    if (EPI == 0) {
        #pragma unroll
        for (int m = 0; m < 4; m++) {
            #pragma unroll
            for (int r2 = 0; r2 < 4; r2++) {
                int pos = row0 + wr + m * 16 + lg * 4 + r2;
                if (pos < nrows) {
                    size_t ho = (size_t)(slotbase + pos) * MDIM;
                    #pragma unroll
                    for (int nn = 0; nn < 4; nn++) {
                        int col = p0 + wc + nn * 16 + lr;
                        float v = acc[m][nn][r2] + bias[col];
                        hmid[ho + col] = f2bf(gelu_f(v));
                    }
                }
            }
        }
    } else {
        #pragma unroll
        for (int m = 0; m < 4; m++) {
            #pragma unroll
            for (int r2 = 0; r2 < 4; r2++) {
                int pos = row0 + wr + m * 16 + lg * 4 + r2;
                if (pos < nrows) {
                    int tokr = lte[pos];
                    float cf = lcfe[pos];
                    float* orow = out + (size_t)tokr * HDIM;
                    #pragma unroll
                    for (int nn = 0; nn < 4; nn++) {
                        int col = p0 + wc + nn * 16 + lr;
                        float v = (acc[m][nn][r2] + bias[col]) * cf;
                        atomicAdd(orow + col, v);
                    }
                }
            }
        }
    }
}

extern "C" void kernel_launch(void* const* d_in, const int* in_sizes, int n_in,
                              void* d_out, int out_size, void* d_ws, size_t ws_size,
                              hipStream_t stream)
{
    const float* x  = (const float*)d_in[0];
    const float* Wr = (const float*)d_in[1];
    const float* br = (const float*)d_in[2];
    const float* W1 = (const float*)d_in[3];
    const float* b1 = (const float*)d_in[4];
    const float* W2 = (const float*)d_in[5];
    const float* b2 = (const float*)d_in[6];
    float* out = (float*)d_out;

    char* ws = (char*)d_ws;
    size_t off = 0;
    auto alloc = [&](size_t bytes) {
        void* p = ws + off;
        off = (off + bytes + 255) & ~(size_t)255;
        return p;
    };
    int*   counts = (int*)  alloc(NEXP * 4);
    int*   bases  = (int*)  alloc(NEXP * 4);
    int*   ltok   = (int*)  alloc((size_t)NEXP * NTOK * 4);
    float* lcf    = (float*)alloc((size_t)NEXP * NTOK * 4);
    u16*   xb     = (u16*)  alloc((size_t)NTOK * HDIM * 2);
    u16*   w1t    = (u16*)  alloc((size_t)NEXP * MDIM * HDIM * 2);
    u16*   w2t    = (u16*)  alloc((size_t)NEXP * HDIM * MDIM * 2);
    size_t fixed_end = off;
    bool grouped = (ws_size >= fixed_end + (size_t)2 * NTOK * MDIM * 2);
    u16* hmid = (u16*)alloc((grouped ? (size_t)2 * NTOK : (size_t)NTOK) * MDIM * 2);

    hipMemsetAsync(counts, 0, NEXP * 4, stream);
    hipMemsetAsync(d_out, 0, (size_t)out_size * sizeof(float), stream);

    // fused W1/W2 transpose+convert: one dispatch, z = 16 expert-slices
    transpose_cvt_kernel<<<dim3((HDIM * MDIM) / 1024, 1, 2 * NEXP), 256, 0, stream>>>(
        W1, W2, w1t, w2t);
    router_kernel<<<NTOK / RTOK, 256, 0, stream>>>(x, Wr, br, counts, ltok, lcf, xb);

    if (grouped) {
        bases_kernel<<<1, 64, 0, stream>>>(counts, bases);
        gemm_kernel<0, MDIM / 128, NTOK / 256>
            <<<dim3(MDIM / 128, NTOK / 256, NEXP), 512, 0, stream>>>(
            xb, w1t, b1, counts, bases, ltok, lcf, hmid, nullptr,
            HDIM, MDIM, HDIM, 0);
        gemm_kernel<1, HDIM / 128, NTOK / 256>
            <<<dim3(HDIM / 128, NTOK / 256, NEXP), 512, 0, stream>>>(
            hmid, w2t, b2, counts, bases, ltok, lcf, nullptr, out,
            MDIM, HDIM, MDIM, 0);
    } else {
        hipMemsetAsync(bases, 0, NEXP * 4, stream);   // slotbase = 0: reuse hmid per expert
        for (int e = 0; e < NEXP; e++) {
            gemm_kernel<0, MDIM / 128, NTOK / 256>
                <<<dim3(MDIM / 128, NTOK / 256, 1), 512, 0, stream>>>(
                xb, w1t, b1, counts, bases, ltok, lcf, hmid, nullptr,
                HDIM, MDIM, HDIM, e);
            gemm_kernel<1, HDIM / 128, NTOK / 256>
                <<<dim3(HDIM / 128, NTOK / 256, 1), 512, 0, stream>>>(
                hmid, w2t, b2, counts, bases, ltok, lcf, nullptr, out,
                MDIM, HDIM, MDIM, e);
        }
    }
}

// Round 19
// 960.212 us; speedup vs baseline: 1.0847x; 1.0847x over previous
//
#include <hip/hip_runtime.h>
#include <hip/hip_bf16.h>
#include <math.h>

#define NTOK 16384   // NS*L = 8*2048
#define HDIM 1024
#define MDIM 4096
#define NEXP 8
#define EPSV 1e-9f
#define RTOK 32      // tokens per router block

typedef unsigned short u16;
typedef __attribute__((ext_vector_type(4))) float f32x4;
typedef __attribute__((ext_vector_type(8))) __bf16 bf16x8;
typedef __attribute__((ext_vector_type(8))) unsigned short u16x8;
typedef __attribute__((ext_vector_type(4))) unsigned short u16x4;

#define ASYNC_COPY16(gptr, lptr) \
    __builtin_amdgcn_global_load_lds( \
        (const __attribute__((address_space(1))) void*)(gptr), \
        (__attribute__((address_space(3))) void*)(lptr), 16, 0, 0)

static __device__ __forceinline__ u16 f2bf(float f) {
    unsigned int u = __builtin_bit_cast(unsigned int, f);
    u += 0x7fff + ((u >> 16) & 1);   // RNE
    return (u16)(u >> 16);
}

// NaN-safe tanh-approx GELU: v * sigmoid(2z), z = sqrt(2/pi)(v + 0.044715 v^3).
static __device__ __forceinline__ float gelu_f(float v) {
    float z2 = -1.5957691216f * v * (1.f + 0.044715f * v * v);
    return v / (1.f + __expf(z2));
}

// ------- router: logits -> softmax -> top2 -> expert lists; also x -> bf16 ---
__global__ __launch_bounds__(256) void router_kernel(
    const float* __restrict__ x, const float* __restrict__ Wr,
    const float* __restrict__ br,
    int* __restrict__ counts, int* __restrict__ ltok, float* __restrict__ lcf,
    u16* __restrict__ xb)
{
    __shared__ int   lcount[NEXP];
    __shared__ int   lbase[NEXP];
    __shared__ int   ltokL[NEXP][RTOK];
    __shared__ float lcfL[NEXP][RTOK];

    int t = threadIdx.x;
    if (t < NEXP) lcount[t] = 0;
    __syncthreads();

    int wave = t >> 6, lane = t & 63;

    for (int it = 0; it < RTOK / 4; ++it) {
        int tok = blockIdx.x * RTOK + it * 4 + wave;
        const float* xr = x + (size_t)tok * HDIM + lane * 16;

        f32x4 xv[4];
        #pragma unroll
        for (int q = 0; q < 4; q++) xv[q] = *reinterpret_cast<const f32x4*>(xr + q * 4);

        u16x8 ob0, ob1;
        #pragma unroll
        for (int j = 0; j < 4; j++) {
            ob0[j]     = f2bf(xv[0][j]);
            ob0[4 + j] = f2bf(xv[1][j]);
            ob1[j]     = f2bf(xv[2][j]);
            ob1[4 + j] = f2bf(xv[3][j]);
        }
        u16* xo = xb + (size_t)tok * HDIM + lane * 16;
        *reinterpret_cast<u16x8*>(xo)     = ob0;
        *reinterpret_cast<u16x8*>(xo + 8) = ob1;

        f32x4 acc0 = {0.f, 0.f, 0.f, 0.f};
        f32x4 acc1 = {0.f, 0.f, 0.f, 0.f};
        #pragma unroll
        for (int q = 0; q < 4; q++) {
            #pragma unroll
            for (int j = 0; j < 4; j++) {
                int h = lane * 16 + q * 4 + j;
                const float* wrow = Wr + (size_t)h * NEXP;
                f32x4 w0 = *reinterpret_cast<const f32x4*>(wrow);
                f32x4 w1 = *reinterpret_cast<const f32x4*>(wrow + 4);
                acc0 += xv[q][j] * w0;
                acc1 += xv[q][j] * w1;
            }
        }
        float a[NEXP];
        #pragma unroll
        for (int e = 0; e < 4; e++) { a[e] = acc0[e]; a[4 + e] = acc1[e]; }
        #pragma unroll
        for (int e = 0; e < NEXP; e++) {
            #pragma unroll
            for (int s = 1; s < 64; s <<= 1) a[e] += __shfl_xor(a[e], s, 64);
        }
        if (lane == 0) {
            float l[NEXP], m = -1e30f;
            #pragma unroll
            for (int e = 0; e < NEXP; e++) { l[e] = a[e] + br[e]; m = fmaxf(m, l[e]); }
            float p[NEXP], s = 0.f;
            #pragma unroll
            for (int e = 0; e < NEXP; e++) { p[e] = expf(l[e] - m); s += p[e]; }
            int i0 = 0; float v0 = p[0];
            #pragma unroll
            for (int e = 1; e < NEXP; e++) if (p[e] > v0) { v0 = p[e]; i0 = e; }
            int i1 = -1; float v1 = -1.f;
            #pragma unroll
            for (int e = 0; e < NEXP; e++) if (e != i0 && p[e] > v1) { v1 = p[e]; i1 = e; }
            v0 /= s; v1 /= s;
            float sw = v0 + v1;
            float w0 = v0 / (sw + EPSV), w1 = v1 / (sw + EPSV);
            float wa = w0 + w1;
            float c0 = w0 / (wa + EPSV), c1 = w1 / (wa + EPSV);
            int q0 = atomicAdd(&lcount[i0], 1);
            ltokL[i0][q0] = tok; lcfL[i0][q0] = c0;
            int q1 = atomicAdd(&lcount[i1], 1);
            ltokL[i1][q1] = tok; lcfL[i1][q1] = c1;
        }
    }
    __syncthreads();
    if (t < NEXP) lbase[t] = atomicAdd(&counts[t], lcount[t]);
    __syncthreads();
    #pragma unroll
    for (int e = 0; e < NEXP; e++) {
        int n = lcount[e], b = lbase[e];
        for (int j = t; j < n; j += 256) {
            ltok[e * NTOK + b + j] = ltokL[e][j];
            lcf[e * NTOK + b + j]  = lcfL[e][j];
        }
    }
}

// ---------------- prefix sum of counts -> slot bases --------------------------
__global__ void bases_kernel(const int* __restrict__ counts, int* __restrict__ bases)
{
    if (threadIdx.x == 0) {
        int acc = 0;
        #pragma unroll
        for (int e = 0; e < NEXP; e++) { bases[e] = acc; acc += counts[e]; }
    }
}

// -------- fused transpose+convert for W1 and W2 (one dispatch, z selects) ----
__global__ __launch_bounds__(256) void transpose_cvt_kernel(
    const float* __restrict__ W1, const float* __restrict__ W2,
    u16* __restrict__ w1t, u16* __restrict__ w2t)
{
    __shared__ float tile[32][33];
    int z = blockIdx.z;
    int R, C;
    const float* ine;
    u16* oute;
    if (z < NEXP) {
        R = HDIM; C = MDIM;
        ine  = W1 + (size_t)z * R * C;
        oute = w1t + (size_t)z * R * C;
    } else {
        R = MDIM; C = HDIM;
        ine  = W2 + (size_t)(z - NEXP) * R * C;
        oute = w2t + (size_t)(z - NEXP) * R * C;
    }
    int tiles_x = C >> 5;
    int ti = blockIdx.x;
    int c0 = (ti & (tiles_x - 1)) * 32;
    int r0 = (ti / tiles_x) * 32;

    int t = threadIdx.x;
    int r = t >> 3, cq = t & 7;
    f32x4 v = *reinterpret_cast<const f32x4*>(ine + (size_t)(r0 + r) * C + c0 + cq * 4);
    #pragma unroll
    for (int j = 0; j < 4; j++) tile[r][cq * 4 + j] = v[j];
    __syncthreads();
    int c = t >> 3, rq = t & 7;
    u16x4 o;
    #pragma unroll
    for (int j = 0; j < 4; j++) o[j] = f2bf(tile[rq * 4 + j][c]);
    *reinterpret_cast<u16x4*>(oute + (size_t)(c0 + c) * R + r0 + rq * 4) = o;
}

// ==== grouped MFMA GEMM: R13-exact (best measured, 961us total).
//      256x128 tile, BK=64, single-buffered (48 KB LDS), 512 threads = 8 waves
//      of 64x64, XCD chunk swizzle (x-fastest), LDS XOR swizzle (128B rows).
// Per K-step per wave: 6 global_load_lds -> __syncthreads -> 16 ds_read_b128
//   + 32 MFMA -> __syncthreads.
// EPI==0: hmid[(bases[e]+pos)][col] = gelu(acc + b1[e][col]); A gathered by ltok
// EPI==1: atomicAdd(out[ltok[pos]][col], lcf[pos]*(acc + b2[e][col]))
template<int EPI, int GX, int GY>
__global__ __launch_bounds__(512) void gemm_kernel(
    const u16* __restrict__ A,          // bf16; row stride = Astride
    const u16* __restrict__ BT_all,     // (NEXP x P x K) bf16
    const float* __restrict__ bias_all, // (NEXP x P)
    const int* __restrict__ counts,
    const int* __restrict__ bases,
    const int* __restrict__ ltok,       // (NEXP x NTOK)
    const float* __restrict__ lcf,      // (NEXP x NTOK)
    u16* __restrict__ hmid,
    float* __restrict__ out,
    int K, int P, int Astride, int eStart)
{
    // ---- XCD chunk swizzle (bijective; nwg % 8 == 0 in all our launches) ----
    int gz = gridDim.z;
    int nwg = GX * GY * gz;
    int orig = blockIdx.x + GX * (blockIdx.y + GY * blockIdx.z);
    int qq = nwg >> 3, rr = nwg & 7;
    int xcd = orig & 7, sub = orig >> 3;
    int wgid = (xcd < rr ? xcd * (qq + 1) : rr * (qq + 1) + (xcd - rr) * qq) + sub;
    int bx = wgid & (GX - 1);
    int rem = wgid / GX;
    int by = rem & (GY - 1);
    int bz = rem / GY;

    int e = eStart + bz;
    int nrows = counts[e];
    int row0 = by * 256;
    if (row0 >= nrows) return;          // uniform across block, before barriers
    int p0 = bx * 128;
    int slotbase = bases[e];
    const u16*   BT   = BT_all + (size_t)e * P * K;
    const float* bias = bias_all + (size_t)e * P;
    const int*   lte  = ltok + (size_t)e * NTOK;
    const float* lcfe = lcf  + (size_t)e * NTOK;

    __shared__ u16 As[256][64];   // 32 KB, single-buffered
    __shared__ u16 Bs[128][64];   // 16 KB

    int t = threadIdx.x;
    int wv = t >> 6, lane = t & 63;     // 8 waves
    int lrow8 = lane >> 3;       // slab row 0..7
    int lcol8 = lane & 7;        // 16B chunk 0..7
    int schunk = lcol8 ^ lrow8;  // pre-swizzled source chunk

    // staging: wave wv covers A rows [wv*32, +32) (4 slabs), B rows [wv*16, +16)
    const u16* aptr[4];
    const u16* bptr[2];
    #pragma unroll
    for (int i = 0; i < 4; i++) {
        int pos  = row0 + wv * 32 + i * 8 + lrow8;
        int posc = min(pos, nrows - 1);
        int arow = (EPI == 0) ? lte[posc] : (slotbase + posc);
        aptr[i] = A + (size_t)arow * Astride + schunk * 8;
    }
    #pragma unroll
    for (int j = 0; j < 2; j++) {
        int prow = p0 + wv * 16 + j * 8 + lrow8;
        bptr[j] = BT + (size_t)prow * K + schunk * 8;
    }

    // output mapping: 8 waves = 4 rows x 2 cols of 64x64 tiles
    int wr = (wv >> 1) * 64, wc = (wv & 1) * 64;
    int lr = lane & 15, lg = lane >> 4;
    int lr7 = lr & 7;

    f32x4 acc[4][4];
    #pragma unroll
    for (int m = 0; m < 4; m++)
        #pragma unroll
        for (int nn = 0; nn < 4; nn++) acc[m][nn] = (f32x4){0.f, 0.f, 0.f, 0.f};

    for (int k0 = 0; k0 < K; k0 += 64) {
        #pragma unroll
        for (int i = 0; i < 4; i++)
            ASYNC_COPY16(aptr[i] + k0, &As[wv * 32 + i * 8][0]);
        #pragma unroll
        for (int j = 0; j < 2; j++)
            ASYNC_COPY16(bptr[j] + k0, &Bs[wv * 16 + j * 8][0]);
        __syncthreads();   // drains vmcnt: tile resident
        #pragma unroll
        for (int kk = 0; kk < 64; kk += 32) {
            int q = kk >> 3;   // logical chunk base (0 or 4)
            bf16x8 af[4], bf[4];
            #pragma unroll
            for (int m = 0; m < 4; m++)
                af[m] = *reinterpret_cast<const bf16x8*>(
                    &As[wr + m * 16 + lr][((q + lg) ^ lr7) * 8]);
            #pragma unroll
            for (int nn = 0; nn < 4; nn++)
                bf[nn] = *reinterpret_cast<const bf16x8*>(
                    &Bs[wc + nn * 16 + lr][((q + lg) ^ lr7) * 8]);
            #pragma unroll
            for (int m = 0; m < 4; m++)
                #pragma unroll
                for (int nn = 0; nn < 4; nn++)
                    acc[m][nn] = __builtin_amdgcn_mfma_f32_16x16x32_bf16(
                        af[m], bf[nn], acc[m][nn], 0, 0, 0);
        }
        __syncthreads();   // reads done before next overwrite
    }

    // D mapping (m89-verified): col = lane&15, row = (lane>>4)*4 + reg
    if (EPI == 0) {
        #pragma unroll
        for (int m = 0; m < 4; m++) {
            #pragma unroll
            for (int r2 = 0; r2 < 4; r2++) {
                int pos = row0 + wr + m * 16 + lg * 4 + r2;
                if (pos < nrows) {
                    size_t ho = (size_t)(slotbase + pos) * MDIM;
                    #pragma unroll
                    for (int nn = 0; nn < 4; nn++) {
                        int col = p0 + wc + nn * 16 + lr;
                        float v = acc[m][nn][r2] + bias[col];
                        hmid[ho + col] = f2bf(gelu_f(v));
                    }
                }
            }
        }
    } else {
        #pragma unroll
        for (int m = 0; m < 4; m++) {
            #pragma unroll
            for (int r2 = 0; r2 < 4; r2++) {
                int pos = row0 + wr + m * 16 + lg * 4 + r2;
                if (pos < nrows) {
                    int tokr = lte[pos];
                    float cf = lcfe[pos];
                    float* orow = out + (size_t)tokr * HDIM;
                    #pragma unroll
                    for (int nn = 0; nn < 4; nn++) {
                        int col = p0 + wc + nn * 16 + lr;
                        float v = (acc[m][nn][r2] + bias[col]) * cf;
                        atomicAdd(orow + col, v);
                    }
                }
            }
        }
    }
}

extern "C" void kernel_launch(void* const* d_in, const int* in_sizes, int n_in,
                              void* d_out, int out_size, void* d_ws, size_t ws_size,
                              hipStream_t stream)
{
    const float* x  = (const float*)d_in[0];
    const float* Wr = (const float*)d_in[1];
    const float* br = (const float*)d_in[2];
    const float* W1 = (const float*)d_in[3];
    const float* b1 = (const float*)d_in[4];
    const float* W2 = (const float*)d_in[5];
    const float* b2 = (const float*)d_in[6];
    float* out = (float*)d_out;

    char* ws = (char*)d_ws;
    size_t off = 0;
    auto alloc = [&](size_t bytes) {
        void* p = ws + off;
        off = (off + bytes + 255) & ~(size_t)255;
        return p;
    };
    int*   counts = (int*)  alloc(NEXP * 4);
    int*   bases  = (int*)  alloc(NEXP * 4);
    int*   ltok   = (int*)  alloc((size_t)NEXP * NTOK * 4);
    float* lcf    = (float*)alloc((size_t)NEXP * NTOK * 4);
    u16*   xb     = (u16*)  alloc((size_t)NTOK * HDIM * 2);
    u16*   w1t    = (u16*)  alloc((size_t)NEXP * MDIM * HDIM * 2);
    u16*   w2t    = (u16*)  alloc((size_t)NEXP * HDIM * MDIM * 2);
    size_t fixed_end = off;
    bool grouped = (ws_size >= fixed_end + (size_t)2 * NTOK * MDIM * 2);
    u16* hmid = (u16*)alloc((grouped ? (size_t)2 * NTOK : (size_t)NTOK) * MDIM * 2);

    hipMemsetAsync(counts, 0, NEXP * 4, stream);
    hipMemsetAsync(d_out, 0, (size_t)out_size * sizeof(float), stream);

    // fused W1/W2 transpose+convert: one dispatch, z = 16 expert-slices
    transpose_cvt_kernel<<<dim3((HDIM * MDIM) / 1024, 1, 2 * NEXP), 256, 0, stream>>>(
        W1, W2, w1t, w2t);
    router_kernel<<<NTOK / RTOK, 256, 0, stream>>>(x, Wr, br, counts, ltok, lcf, xb);

    if (grouped) {
        bases_kernel<<<1, 64, 0, stream>>>(counts, bases);
        gemm_kernel<0, MDIM / 128, NTOK / 256>
            <<<dim3(MDIM / 128, NTOK / 256, NEXP), 512, 0, stream>>>(
            xb, w1t, b1, counts, bases, ltok, lcf, hmid, nullptr,
            HDIM, MDIM, HDIM, 0);
        gemm_kernel<1, HDIM / 128, NTOK / 256>
            <<<dim3(HDIM / 128, NTOK / 256, NEXP), 512, 0, stream>>>(
            hmid, w2t, b2, counts, bases, ltok, lcf, nullptr, out,
            MDIM, HDIM, MDIM, 0);
    } else {
        hipMemsetAsync(bases, 0, NEXP * 4, stream);   // slotbase = 0: reuse hmid per expert
        for (int e = 0; e < NEXP; e++) {
            gemm_kernel<0, MDIM / 128, NTOK / 256>
                <<<dim3(MDIM / 128, NTOK / 256, 1), 512, 0, stream>>>(
                xb, w1t, b1, counts, bases, ltok, lcf, hmid, nullptr,
                HDIM, MDIM, HDIM, e);
            gemm_kernel<1, HDIM / 128, NTOK / 256>
                <<<dim3(HDIM / 128, NTOK / 256, 1), 512, 0, stream>>>(
                hmid, w2t, b2, counts, bases, ltok, lcf, nullptr, out,
                MDIM, HDIM, MDIM, e);
        }
    }
}